// Round 1
// baseline (121.007 us; speedup 1.0000x reference)
//
#include <hip/hip_runtime.h>
#include <math.h>

#define BN 256      // batch
#define CN 2048     // channels
#define C4 512      // CN/4

// ---------------------------------------------------------------------------
// Kernel 1: per-row center-subtract + L2 normalize.
// One block per row i (256 blocks x 256 threads). Center = mean of rows whose
// target matches targets[B-4] (the last center). Each thread owns 8 columns.
// ---------------------------------------------------------------------------
__global__ __launch_bounds__(256) void prep_kernel(const float* __restrict__ in,
                                                   const int* __restrict__ targets,
                                                   float* __restrict__ V) {
    const int i   = blockIdx.x;
    const int tid = threadIdx.x;

    __shared__ int   s_idx[64];
    __shared__ int   s_cnt;
    __shared__ float s_red[4];
    __shared__ float s_inv;

    if (tid == 0) s_cnt = 0;
    __syncthreads();
    const int tc = targets[BN - 4];          // last center's target id
    if (tid < BN && targets[tid] == tc) {
        int p = atomicAdd(&s_cnt, 1);
        s_idx[p] = tid;
    }
    __syncthreads();
    const int   cnt     = s_cnt;
    const float inv_cnt = 1.0f / (float)cnt;

    float v[8];
    float ss = 0.f;
#pragma unroll
    for (int t = 0; t < 8; ++t) {
        const int c = tid + t * 256;
        float ctr = 0.f;
        for (int m = 0; m < cnt; ++m) ctr += in[s_idx[m] * CN + c];
        ctr *= inv_cnt;
        const float x = in[i * CN + c] - ctr;
        v[t] = x;
        ss += x * x;
    }
    // wave64 butterfly then cross-wave via LDS
#pragma unroll
    for (int off = 32; off >= 1; off >>= 1) ss += __shfl_xor(ss, off, 64);
    const int wave = tid >> 6;
    if ((tid & 63) == 0) s_red[wave] = ss;
    __syncthreads();
    if (tid == 0) {
        const float tot = s_red[0] + s_red[1] + s_red[2] + s_red[3];
        s_inv = 1.0f / fmaxf(sqrtf(tot), 1e-12f);
    }
    __syncthreads();
    const float inv = s_inv;
#pragma unroll
    for (int t = 0; t < 8; ++t) {
        const int c = tid + t * 256;
        V[i * CN + c] = v[t] * inv;
    }
}

// ---------------------------------------------------------------------------
// Kernel 2: Gram matrix G = V @ V^T (256x256, K=2048).
// 256 blocks: block handles 4 consecutive i-rows (staged in 32 KB LDS) x a
// 64-wide j chunk. Each wave owns 16 j's; the 64 lanes cooperatively dot
// over K with coalesced float4 global loads of V[j], wave-reduce, write G.
// ---------------------------------------------------------------------------
__global__ __launch_bounds__(256) void gram_kernel(const float* __restrict__ V,
                                                   float* __restrict__ G) {
    const int blk = blockIdx.x;
    const int i0  = (blk >> 2) * 4;
    const int j0  = (blk & 3) * 64;
    const int tid = threadIdx.x;

    __shared__ float4 sA[4 * C4];            // 4 rows x 2048 floats = 32 KB

    const float4* V4 = (const float4*)V;
    for (int t = tid; t < 4 * C4; t += 256)  // rows are contiguous in V
        sA[t] = V4[i0 * C4 + t];
    __syncthreads();

    const int lane = tid & 63;
    const int wave = tid >> 6;

    for (int s = 0; s < 16; ++s) {
        const int j = j0 + wave + 4 * s;
        float a0 = 0.f, a1 = 0.f, a2 = 0.f, a3 = 0.f;
#pragma unroll
        for (int t = 0; t < 8; ++t) {
            const int k4 = lane + 64 * t;
            const float4 b  = V4[j * C4 + k4];
            const float4 x0 = sA[0 * C4 + k4];
            const float4 x1 = sA[1 * C4 + k4];
            const float4 x2 = sA[2 * C4 + k4];
            const float4 x3 = sA[3 * C4 + k4];
            a0 += x0.x * b.x + x0.y * b.y + x0.z * b.z + x0.w * b.w;
            a1 += x1.x * b.x + x1.y * b.y + x1.z * b.z + x1.w * b.w;
            a2 += x2.x * b.x + x2.y * b.y + x2.z * b.z + x2.w * b.w;
            a3 += x3.x * b.x + x3.y * b.y + x3.z * b.z + x3.w * b.w;
        }
#pragma unroll
        for (int off = 32; off >= 1; off >>= 1) {
            a0 += __shfl_xor(a0, off, 64);
            a1 += __shfl_xor(a1, off, 64);
            a2 += __shfl_xor(a2, off, 64);
            a3 += __shfl_xor(a3, off, 64);
        }
        if (lane < 4) {
            const float val = (lane == 0) ? a0 : (lane == 1) ? a1
                            : (lane == 2) ? a2 : a3;
            G[(i0 + lane) * BN + j] = val;
        }
    }
}

// ---------------------------------------------------------------------------
// Kernel 3: pos/neg per row + final reduction. One block, thread i = row i.
// ---------------------------------------------------------------------------
__global__ __launch_bounds__(256) void finish_kernel(const float* __restrict__ G,
                                                     const int* __restrict__ targets,
                                                     float* __restrict__ out) {
    const int tid = threadIdx.x;
    __shared__ int   s_t[BN];
    __shared__ float s_red[4];

    s_t[tid] = targets[tid];
    __syncthreads();
    const int ti = s_t[tid];

    float pos = INFINITY;
    float neg = 0.f;
    for (int j = 0; j < BN; ++j) {
        const float g = G[tid * BN + j];
        if (s_t[j] == ti) pos = fminf(pos, g);
        else              neg = fmaxf(neg, fmaxf(g, 0.f));
    }
    float val = expf(neg - pos);
#pragma unroll
    for (int off = 32; off >= 1; off >>= 1) val += __shfl_xor(val, off, 64);
    const int wave = tid >> 6;
    if ((tid & 63) == 0) s_red[wave] = val;
    __syncthreads();
    if (tid == 0)
        out[0] = (s_red[0] + s_red[1] + s_red[2] + s_red[3]) * (1.0f / 448.0f);
}

extern "C" void kernel_launch(void* const* d_in, const int* in_sizes, int n_in,
                              void* d_out, int out_size, void* d_ws, size_t ws_size,
                              hipStream_t stream) {
    const float* in      = (const float*)d_in[0];
    const int*   targets = (const int*)d_in[1];
    // d_in[2] (subs) is unused by the reference.

    float* V = (float*)d_ws;                 // 256*2048 floats = 2 MB
    float* G = V + BN * CN;                  // 256*256 floats  = 256 KB
    float* out = (float*)d_out;

    prep_kernel  <<<BN,  256, 0, stream>>>(in, targets, V);
    gram_kernel  <<<BN,  256, 0, stream>>>(V, G);
    finish_kernel<<<1,   256, 0, stream>>>(G, targets, out);
}

// Round 2
// 91.669 us; speedup vs baseline: 1.3201x; 1.3201x over previous
//
#include <hip/hip_runtime.h>
#include <math.h>

#define BN 256      // batch
#define CN 2048     // channels
#define C4 512      // CN/4
#define EPSF 1e-12f

// ---------------------------------------------------------------------------
// Kernel A: raw Gram D = in @ in^T  (256x256, K=2048), fp32.
// 512 blocks: block = 4 i-rows x 32 j-cols. Wave's k-slice of the 4 i-rows
// lives in 128 VGPRs (wave-invariant across j). Per j: 8 coalesced float4
// global loads of row j (L2-resident), 128 FMAs, 64-lane butterfly, store.
// ---------------------------------------------------------------------------
__global__ __launch_bounds__(256) void gram_kernel(const float* __restrict__ in,
                                                   float* __restrict__ D) {
    const int b    = blockIdx.x;
    const int i0   = (b >> 3) * 4;
    const int j0   = (b & 7) * 32;
    const int tid  = threadIdx.x;
    const int lane = tid & 63;
    const int wave = tid >> 6;

    const float4* __restrict__ in4 = (const float4*)in;

    float4 a[4][8];
#pragma unroll
    for (int r = 0; r < 4; ++r)
#pragma unroll
        for (int t = 0; t < 8; ++t)
            a[r][t] = in4[(i0 + r) * C4 + lane + 64 * t];

#pragma unroll 2
    for (int s = 0; s < 8; ++s) {
        const int j = j0 + wave + 4 * s;
        float4 bv[8];
#pragma unroll
        for (int t = 0; t < 8; ++t)
            bv[t] = in4[j * C4 + lane + 64 * t];

        float a0 = 0.f, a1 = 0.f, a2 = 0.f, a3 = 0.f;
#pragma unroll
        for (int t = 0; t < 8; ++t) {
            const float4 b4 = bv[t];
            a0 += a[0][t].x * b4.x + a[0][t].y * b4.y + a[0][t].z * b4.z + a[0][t].w * b4.w;
            a1 += a[1][t].x * b4.x + a[1][t].y * b4.y + a[1][t].z * b4.z + a[1][t].w * b4.w;
            a2 += a[2][t].x * b4.x + a[2][t].y * b4.y + a[2][t].z * b4.z + a[2][t].w * b4.w;
            a3 += a[3][t].x * b4.x + a[3][t].y * b4.y + a[3][t].z * b4.z + a[3][t].w * b4.w;
        }
#pragma unroll
        for (int off = 32; off >= 1; off >>= 1) {
            a0 += __shfl_xor(a0, off, 64);
            a1 += __shfl_xor(a1, off, 64);
            a2 += __shfl_xor(a2, off, 64);
            a3 += __shfl_xor(a3, off, 64);
        }
        if (lane < 4) {
            const float val = (lane == 0) ? a0 : (lane == 1) ? a1
                            : (lane == 2) ? a2 : a3;
            D[(i0 + lane) * BN + j] = val;
        }
    }
}

// ---------------------------------------------------------------------------
// Kernel B: everything else from D. One block, thread i = row i.
//   s_i  = mean over center rows m of D[i,m]
//   cc   = mean over center rows m of s_m          (= ||c||^2)
//   nrm2 = D[i,i] - 2 s_i + cc                     (= ||in_i - c||^2)
//   angle[i,j] = (D[i,j] - s_i - s_j + cc) * inv_i * inv_j
//   pos/neg/exp/sum as in the reference (only the LAST center is returned).
// ---------------------------------------------------------------------------
__global__ __launch_bounds__(256) void finish_kernel(const float* __restrict__ D,
                                                     const int* __restrict__ targets,
                                                     float* __restrict__ out) {
    const int tid = threadIdx.x;
    __shared__ int   s_t[BN];
    __shared__ float s_s[BN];
    __shared__ float s_inv[BN];
    __shared__ int   s_idx[64];
    __shared__ int   s_cnt;
    __shared__ float s_cc;
    __shared__ float s_red[4];

    if (tid == 0) s_cnt = 0;
    s_t[tid] = targets[tid];
    __syncthreads();
    const int tc = s_t[BN - 4];                  // last center's target id
    if (s_t[tid] == tc) { int p = atomicAdd(&s_cnt, 1); s_idx[p] = tid; }
    __syncthreads();
    const int   cnt  = s_cnt;
    const float invc = 1.0f / (float)cnt;

    float si = 0.f;
    for (int m = 0; m < cnt; ++m) si += D[tid * BN + s_idx[m]];
    si *= invc;
    s_s[tid] = si;
    __syncthreads();
    if (tid == 0) {
        float cc = 0.f;
        for (int m = 0; m < cnt; ++m) cc += s_s[s_idx[m]];
        s_cc = cc * invc;
    }
    __syncthreads();
    const float cc   = s_cc;
    const float dii  = D[tid * BN + tid];
    const float nrm2 = fmaxf(dii - 2.f * si + cc, 0.f);
    const float inv  = 1.0f / fmaxf(sqrtf(nrm2), EPSF);
    s_inv[tid] = inv;
    __syncthreads();

    const int ti = s_t[tid];
    float pos = INFINITY;
    float neg = 0.f;
    const float4* __restrict__ D4 = (const float4*)D;
    for (int j4 = 0; j4 < BN / 4; ++j4) {
        const float4 d = D4[tid * (BN / 4) + j4];
        const int j = 4 * j4;
        const float g0 = (d.x - si - s_s[j + 0] + cc) * inv * s_inv[j + 0];
        const float g1 = (d.y - si - s_s[j + 1] + cc) * inv * s_inv[j + 1];
        const float g2 = (d.z - si - s_s[j + 2] + cc) * inv * s_inv[j + 2];
        const float g3 = (d.w - si - s_s[j + 3] + cc) * inv * s_inv[j + 3];
        if (s_t[j + 0] == ti) pos = fminf(pos, g0); else neg = fmaxf(neg, fmaxf(g0, 0.f));
        if (s_t[j + 1] == ti) pos = fminf(pos, g1); else neg = fmaxf(neg, fmaxf(g1, 0.f));
        if (s_t[j + 2] == ti) pos = fminf(pos, g2); else neg = fmaxf(neg, fmaxf(g2, 0.f));
        if (s_t[j + 3] == ti) pos = fminf(pos, g3); else neg = fmaxf(neg, fmaxf(g3, 0.f));
    }
    float val = expf(neg - pos);
#pragma unroll
    for (int off = 32; off >= 1; off >>= 1) val += __shfl_xor(val, off, 64);
    const int wave = tid >> 6;
    if ((tid & 63) == 0) s_red[wave] = val;
    __syncthreads();
    if (tid == 0)
        out[0] = (s_red[0] + s_red[1] + s_red[2] + s_red[3]) * (1.0f / 448.0f);
}

extern "C" void kernel_launch(void* const* d_in, const int* in_sizes, int n_in,
                              void* d_out, int out_size, void* d_ws, size_t ws_size,
                              hipStream_t stream) {
    const float* in      = (const float*)d_in[0];
    const int*   targets = (const int*)d_in[1];
    // d_in[2] (subs) is unused by the reference.

    float* D   = (float*)d_ws;               // 256*256 floats = 256 KB
    float* out = (float*)d_out;

    gram_kernel  <<<512, 256, 0, stream>>>(in, D);
    finish_kernel<<<1,   256, 0, stream>>>(D, targets, out);
}